// Round 9
// baseline (943.201 us; speedup 1.0000x reference)
//
#include <hip/hip_runtime.h>
#include <stdint.h>

#define L_ 8
#define D_ 256
#define H_ 8
#define DK_ 32
#define FF_ 1024
#define R_ 37
#define N_ 1024

// scale * log2(e): attention runs in exp2 domain
#define SCL (0.17677669529663689f * 1.4426950408889634f)

typedef float f4v __attribute__((ext_vector_type(4)));
typedef short b8v __attribute__((ext_vector_type(8)));

__device__ __forceinline__ ushort f2b(float f){
  union { float f; uint32_t u; } x; x.f = f;
  return (ushort)((x.u + 0x7FFFu + ((x.u >> 16) & 1u)) >> 16);
}
__device__ __forceinline__ float b2f(ushort u){
  union { uint32_t u; float f; } x; x.u = ((uint32_t)u) << 16;
  return x.f;
}
__device__ __forceinline__ ushort f2h(float f){
  union { _Float16 h; ushort u; } x; x.h = (_Float16)f;
  return x.u;
}
__device__ __forceinline__ float h2f(ushort u){
  union { ushort u; _Float16 h; } x; x.u = u;
  return (float)x.h;
}
__device__ __forceinline__ float ex2(float x){ return __builtin_amdgcn_exp2f(x); }

// native LDS float add (fire-and-forget). DS pipe is in-order per wave, so a
// later ds_read by the same wave sees these adds without extra sync.
__device__ __forceinline__ void lds_fadd(float* p, float v){
  asm volatile("ds_add_f32 %0, %1" :: "v"((uint)(uintptr_t)p), "v"(v) : "memory");
}

// ---------------- weight transpose + cast: src [L][K][Nc] f32 -> dst [L][Nc][K] bf16
__global__ __launch_bounds__(256)
void wcast_kernel(const float* __restrict__ src, ushort* __restrict__ dst, int K, int Nc){
  __shared__ float t[32][33];
  int l = blockIdx.z;
  long base = (long)l * K * Nc;
  int n0 = blockIdx.x * 32, k0 = blockIdx.y * 32;
  int tx = threadIdx.x, ty = threadIdx.y; // (32,8)
  #pragma unroll
  for (int r = 0; r < 32; r += 8)
    t[ty + r][tx] = src[base + (long)(k0 + ty + r) * Nc + n0 + tx];
  __syncthreads();
  #pragma unroll
  for (int r = 0; r < 32; r += 8)
    dst[base + (long)(n0 + ty + r) * K + k0 + tx] = f2b(t[tx][ty + r]);
}

// ---------------- rel int32 -> uint8 (values < 37), once per call
__global__ __launch_bounds__(256)
void rel8_kernel(const int* __restrict__ rel, uint* __restrict__ rel8){
  long idx = (long)blockIdx.x * 256 + threadIdx.x;
  int4 v = ((const int4*)rel)[idx];
  rel8[idx] = (uint)(v.x & 255) | ((uint)(v.y & 255) << 8)
            | ((uint)(v.z & 255) << 16) | ((uint)(v.w & 255) << 24);
}

// ---------------- LayerNorm
template<int OUTB>
__global__ __launch_bounds__(64)
void ln_kernel(const float* __restrict__ x, const float* __restrict__ g, const float* __restrict__ b,
               ushort* __restrict__ ob, float* __restrict__ of){
  int row = blockIdx.x, lane = threadIdx.x;
  float4 v = ((const float4*)(x + (long)row * D_))[lane];
  float s = v.x + v.y + v.z + v.w;
  float s2 = v.x*v.x + v.y*v.y + v.z*v.z + v.w*v.w;
  #pragma unroll
  for (int o = 32; o; o >>= 1){ s += __shfl_xor(s, o); s2 += __shfl_xor(s2, o); }
  float mu = s * (1.f / D_);
  float var = (s2 - D_ * mu * mu) * (1.f / (D_ - 1));
  var = fmaxf(var, 0.f);
  float inv = 1.f / (sqrtf(var) + 1e-6f);
  float4 gv = ((const float4*)g)[lane];
  float4 bv = ((const float4*)b)[lane];
  float o0 = gv.x * (v.x - mu) * inv + bv.x;
  float o1 = gv.y * (v.y - mu) * inv + bv.y;
  float o2 = gv.z * (v.z - mu) * inv + bv.z;
  float o3 = gv.w * (v.w - mu) * inv + bv.w;
  if (OUTB){
    ushort4 u; u.x = f2b(o0); u.y = f2b(o1); u.z = f2b(o2); u.w = f2b(o3);
    ((ushort4*)ob)[(long)row * 64 + lane] = u;
  } else {
    float4 o; o.x = o0; o.y = o1; o.z = o2; o.w = o3;
    ((float4*)of)[(long)row * 64 + lane] = o;
  }
}

// ---------------- bf16 MFMA GEMM.
// QKV mode: head-split q/k to outB, V^T to outB2.
// OUTH mode: batched (blockIdx.z) scores pass: out f16, transposed store
//            S[col][row] (col = B-row = i, row = A-row = j), no bias.
template<int QKV, int RELU, int RESID, int OUTF, int OUTB, int OUTH = 0>
__global__ __launch_bounds__(256)
void gemm_kernel(const ushort* __restrict__ A,
                 const ushort* __restrict__ W0, const ushort* __restrict__ W1p, const ushort* __restrict__ W2p,
                 const float* __restrict__ B0, const float* __restrict__ B1p, const float* __restrict__ B2p,
                 float* __restrict__ resid, float* __restrict__ outF, ushort* __restrict__ outB,
                 ushort* __restrict__ outB2,
                 int M, int Nc, int K, long aB, long wB, long oB){
  __shared__ ushort Al[64 * 48];
  __shared__ ushort Bl[64 * 48];
  int tid = threadIdx.x;
  int lane = tid & 63, w = tid >> 6;
  int wm = w >> 1, wn = w & 1;
  int bn0 = blockIdx.x * 64, bm0 = blockIdx.y * 64;
  long zb = blockIdx.z;
  A += zb * aB;
  const ushort* WT; const float* bias; int wn0;
  if (QKV){
    int which = bn0 >> 8;
    WT = which == 0 ? W0 : (which == 1 ? W1p : W2p);
    bias = which == 0 ? B0 : (which == 1 ? B1p : B2p);
    wn0 = bn0 & 255;
  } else { WT = W0; bias = B0; wn0 = bn0; }
  WT += zb * wB;

  int r4 = tid >> 2, c8 = (tid & 3) * 8;
  const ushort* ag = A + (long)(bm0 + r4) * K + c8;
  const ushort* bg = WT + (long)(wn0 + r4) * K + c8;

  f4v acc[2][2];
  #pragma unroll
  for (int i = 0; i < 2; ++i)
    #pragma unroll
    for (int j = 0; j < 2; ++j)
      acc[i][j] = (f4v){0.f, 0.f, 0.f, 0.f};

  int l16 = lane & 15, lg = lane >> 4;
  int arow0 = (wm * 32 + l16) * 48 + lg * 8;
  int brow0 = (wn * 32 + l16) * 48 + lg * 8;

  for (int k0 = 0; k0 < K; k0 += 32){
    b8v a8 = *(const b8v*)(ag + k0);
    b8v b8 = *(const b8v*)(bg + k0);
    __syncthreads();
    *(b8v*)&Al[r4 * 48 + c8] = a8;
    *(b8v*)&Bl[r4 * 48 + c8] = b8;
    __syncthreads();
    b8v a0 = *(const b8v*)&Al[arow0];
    b8v a1 = *(const b8v*)&Al[arow0 + 16 * 48];
    b8v b0 = *(const b8v*)&Bl[brow0];
    b8v b1 = *(const b8v*)&Bl[brow0 + 16 * 48];
    acc[0][0] = __builtin_amdgcn_mfma_f32_16x16x32_bf16(a0, b0, acc[0][0], 0, 0, 0);
    acc[0][1] = __builtin_amdgcn_mfma_f32_16x16x32_bf16(a0, b1, acc[0][1], 0, 0, 0);
    acc[1][0] = __builtin_amdgcn_mfma_f32_16x16x32_bf16(a1, b0, acc[1][0], 0, 0, 0);
    acc[1][1] = __builtin_amdgcn_mfma_f32_16x16x32_bf16(a1, b1, acc[1][1], 0, 0, 0);
  }
  #pragma unroll
  for (int fi = 0; fi < 2; ++fi)
    #pragma unroll
    for (int fj = 0; fj < 2; ++fj){
      int row0 = bm0 + wm * 32 + fi * 16 + lg * 4;
      int col = bn0 + wn * 32 + fj * 16 + l16;
      if (OUTH){
        ushort4 pk;
        pk.x = f2h(acc[fi][fj][0]); pk.y = f2h(acc[fi][fj][1]);
        pk.z = f2h(acc[fi][fj][2]); pk.w = f2h(acc[fi][fj][3]);
        *(ushort4*)(outB + zb * oB + (long)col * 1024 + row0) = pk;
        continue;
      }
      float vv[4];
      #pragma unroll
      for (int j = 0; j < 4; ++j) vv[j] = acc[fi][fj][j] + bias[QKV ? (col & 255) : col];
      if (QKV){
        int which = col >> 8, hh = (col >> 5) & 7, dk = col & 31;
        if (which == 2){
          ushort4 pk; pk.x = f2b(vv[0]); pk.y = f2b(vv[1]); pk.z = f2b(vv[2]); pk.w = f2b(vv[3]);
          *(ushort4*)(outB2 + (long)hh * 32768 + (long)dk * 1024 + row0) = pk;
        } else {
          #pragma unroll
          for (int j = 0; j < 4; ++j)
            outB[(long)which * 262144 + (long)hh * 32768 + (long)(row0 + j) * 32 + dk] = f2b(vv[j]);
        }
      } else {
        #pragma unroll
        for (int j = 0; j < 4; ++j){
          float v = vv[j];
          if (RELU) v = fmaxf(v, 0.f);
          long idx = (long)(row0 + j) * Nc + col;
          if (RESID) v += resid[idx];
          if (OUTF) outF[idx] = v;
          if (OUTB) outB[idx] = f2b(v);
        }
      }
    }
}

// ---------------- qr[h][i][r] (padded to 40) = SCL * q[h,i,:] . rel_k_emb[r]
__global__ __launch_bounds__(320)
void qr_kernel(const ushort* __restrict__ qb, const float* __restrict__ rke, float* __restrict__ qr){
  __shared__ float ql[256];
  int i = blockIdx.x, t = threadIdx.x;
  if (t < 256){
    int h = t >> 5, dk = t & 31;
    ql[t] = b2f(qb[(long)((h << 10) + i) * 32 + dk]);
  }
  __syncthreads();
  if (t < H_ * R_){
    int h = t / R_, r = t - h * R_;
    const float* qh = &ql[h * DK_];
    const float* e = rke + r * DK_;
    float acc = 0.f;
    #pragma unroll
    for (int d = 0; d < DK_; ++d) acc += qh[d] * e[d];
    qr[((long)(h << 10) + i) * 40 + r] = acc * SCL;
  }
}

// ---------------- softmax pass: one wave per (head, row). Exact full-row softmax.
// reads S f16 row + rel8 row + qr row; writes normalized P bf16 + o2 = bins@rve / l
__global__ __launch_bounds__(256)
void sm_kernel(const ushort* __restrict__ S, const float* __restrict__ qr,
               const unsigned char* __restrict__ rel8, const float* __restrict__ rve,
               ushort* __restrict__ P, float* __restrict__ o2){
  __shared__ float qrl[4][40];
  __shared__ float bins[4][44];
  int tid = threadIdx.x, lane = tid & 63, w = tid >> 6;
  int h = blockIdx.y, i = blockIdx.x * 4 + w;
  long rowq = (long)(h << 10) + i;

  if (lane < 40) qrl[w][lane] = qr[rowq * 40 + lane];
  if (lane < 44) bins[w][lane] = 0.f;

  const ushort* Srow = S + rowq * 1024 + lane * 16;
  b8v s0 = *(const b8v*)Srow;
  b8v s1 = *(const b8v*)(Srow + 8);
  uint4 rr = *(const uint4*)(rel8 + (long)i * 1024 + lane * 16);
  uint rw[4] = { rr.x, rr.y, rr.z, rr.w };

  int rix[16];
  #pragma unroll
  for (int q = 0; q < 4; ++q)
    #pragma unroll
    for (int e = 0; e < 4; ++e)
      rix[q * 4 + e] = (rw[q] >> (8 * e)) & 255;

  float sv[16];
  #pragma unroll
  for (int e = 0; e < 8; ++e){
    sv[e]     = h2f((ushort)s0[e]) * SCL + qrl[w][rix[e]];
    sv[8 + e] = h2f((ushort)s1[e]) * SCL + qrl[w][rix[8 + e]];
  }
  float m = sv[0];
  #pragma unroll
  for (int e = 1; e < 16; ++e) m = fmaxf(m, sv[e]);
  #pragma unroll
  for (int o = 1; o < 64; o <<= 1) m = fmaxf(m, __shfl_xor(m, o));

  float p[16], ls = 0.f;
  #pragma unroll
  for (int e = 0; e < 16; ++e){ p[e] = ex2(sv[e] - m); ls += p[e]; }
  #pragma unroll
  for (int o = 1; o < 64; o <<= 1) ls += __shfl_xor(ls, o);
  float rinv = 1.f / ls;

  #pragma unroll
  for (int e = 0; e < 16; ++e) lds_fadd(&bins[w][rix[e]], p[e]);

  // normalized P bf16
  b8v po0, po1;
  #pragma unroll
  for (int e = 0; e < 8; ++e){
    po0[e] = (short)f2b(p[e] * rinv);
    po1[e] = (short)f2b(p[8 + e] * rinv);
  }
  *(b8v*)(P + rowq * 1024 + lane * 16) = po0;
  *(b8v*)(P + rowq * 1024 + lane * 16 + 8) = po1;

  // o2[rowq][d] = (bins @ rve)[d] / l   (DS pipe in-order: fadds above are visible)
  int d = lane & 31, half = lane >> 5;
  float acc = 0.f;
  int r0 = half * 19, r1 = r0 + 19 < R_ ? r0 + 19 : R_;
  for (int r = r0; r < r1; ++r) acc += bins[w][r] * rve[r * 32 + d];
  acc += __shfl_xor(acc, 32);
  if (lane < 32) o2[rowq * 32 + d] = acc * rinv;
}

// ---------------- PV pass: O[h][i][d] = P[h][i][:] @ V^T[h][d][:] + o2, staged-LDS GEMM
// grid (N/64, H), 256 threads = 4 waves (each: 16 i-rows x 32 d)
__global__ __launch_bounds__(256)
void pv_kernel(const ushort* __restrict__ P, const ushort* __restrict__ vbt,
               const float* __restrict__ o2, ushort* __restrict__ ob){
  __shared__ ushort Al[64 * 48];
  __shared__ ushort Bl[32 * 48];
  int tid = threadIdx.x, lane = tid & 63, w = tid >> 6;
  int l16 = lane & 15, g = lane >> 4;
  int i0 = blockIdx.x * 64, h = blockIdx.y;
  const ushort* Ph = P + (long)h * 1024 * 1024;
  const ushort* Vh = vbt + (long)h * 32 * 1024;
  int r4 = tid >> 2, c8 = (tid & 3) * 8;

  f4v acc0 = (f4v){0,0,0,0}, acc1 = (f4v){0,0,0,0};
  int arow = (w * 16 + l16) * 48 + g * 8;
  int brow0 = l16 * 48 + g * 8, brow1 = (16 + l16) * 48 + g * 8;

  for (int k0 = 0; k0 < 1024; k0 += 32){
    b8v a8 = *(const b8v*)(Ph + (long)(i0 + r4) * 1024 + k0 + c8);
    b8v b8;
    if (tid < 128) b8 = *(const b8v*)(Vh + (long)r4 * 1024 + k0 + c8);
    __syncthreads();
    *(b8v*)&Al[r4 * 48 + c8] = a8;
    if (tid < 128) *(b8v*)&Bl[r4 * 48 + c8] = b8;
    __syncthreads();
    b8v a0 = *(const b8v*)&Al[arow];
    b8v b0 = *(const b8v*)&Bl[brow0];
    b8v b1 = *(const b8v*)&Bl[brow1];
    acc0 = __builtin_amdgcn_mfma_f32_16x16x32_bf16(a0, b0, acc0, 0, 0, 0);
    acc1 = __builtin_amdgcn_mfma_f32_16x16x32_bf16(a0, b1, acc1, 0, 0, 0);
  }
  #pragma unroll
  for (int e = 0; e < 4; ++e){
    int i = i0 + w * 16 + g * 4 + e;
    long ob2 = ((long)(h << 10) + i) * 32;
    float v0 = acc0[e] + o2[ob2 + l16];
    float v1 = acc1[e] + o2[ob2 + 16 + l16];
    ob[(long)i * 256 + h * 32 + l16] = f2b(v0);
    ob[(long)i * 256 + h * 32 + 16 + l16] = f2b(v1);
  }
}

extern "C" void kernel_launch(void* const* d_in, const int* in_sizes, int n_in,
                              void* d_out, int out_size, void* d_ws, size_t ws_size,
                              hipStream_t stream){
  const float* x    = (const float*)d_in[0];
  const int*   rel  = (const int*)d_in[1];
  const float* Wq   = (const float*)d_in[2];
  const float* bq   = (const float*)d_in[3];
  const float* Wk   = (const float*)d_in[4];
  const float* bk   = (const float*)d_in[5];
  const float* Wv   = (const float*)d_in[6];
  const float* bv   = (const float*)d_in[7];
  const float* Wo   = (const float*)d_in[8];
  const float* bo   = (const float*)d_in[9];
  const float* rke  = (const float*)d_in[10];
  const float* rve  = (const float*)d_in[11];
  const float* W1   = (const float*)d_in[12];
  const float* b1   = (const float*)d_in[13];
  const float* W2   = (const float*)d_in[14];
  const float* b2   = (const float*)d_in[15];
  const float* ln1g = (const float*)d_in[16];
  const float* ln1b = (const float*)d_in[17];
  const float* ln2g = (const float*)d_in[18];
  const float* ln2b = (const float*)d_in[19];
  const float* lnfg = (const float*)d_in[20];
  const float* lnfb = (const float*)d_in[21];

  char* wsb = (char*)d_ws;
  size_t off = 0;
  auto alloc = [&](size_t bytes){ void* p = wsb + off; off += (bytes + 255) & ~255ull; return p; };
  float*  xw   = (float*) alloc((size_t)N_ * D_ * 4);
  ushort* qkvb = (ushort*)alloc((size_t)3 * H_ * N_ * DK_ * 2);
  ushort* vbt  = (ushort*)alloc((size_t)H_ * DK_ * N_ * 2);
  float*  qr   = (float*) alloc((size_t)H_ * N_ * 40 * 4);
  ushort* xnb  = (ushort*)alloc((size_t)N_ * D_ * 2);
  ushort* obf  = (ushort*)alloc((size_t)N_ * D_ * 2);
  ushort* hidb = (ushort*)alloc((size_t)N_ * FF_ * 2);
  uint*   rel8 = (uint*)  alloc((size_t)N_ * N_);
  ushort* Sbuf = (ushort*)alloc((size_t)H_ * N_ * N_ * 2);
  ushort* Pbuf = (ushort*)alloc((size_t)H_ * N_ * N_ * 2);
  float*  o2b  = (float*) alloc((size_t)H_ * N_ * DK_ * 4);
  ushort* wqT  = (ushort*)alloc((size_t)L_ * D_ * D_ * 2);
  ushort* wkT  = (ushort*)alloc((size_t)L_ * D_ * D_ * 2);
  ushort* wvT  = (ushort*)alloc((size_t)L_ * D_ * D_ * 2);
  ushort* woT  = (ushort*)alloc((size_t)L_ * D_ * D_ * 2);
  ushort* w1T  = (ushort*)alloc((size_t)L_ * D_ * FF_ * 2);
  ushort* w2T  = (ushort*)alloc((size_t)L_ * D_ * FF_ * 2);
  (void)ws_size; (void)in_sizes; (void)n_in; (void)out_size;

  ushort* qb = qkvb;
  ushort* kb = qkvb + (size_t)H_ * N_ * DK_;

  dim3 tb(32, 8);
  wcast_kernel<<<dim3(D_/32,  D_/32,  L_), tb, 0, stream>>>(Wq, wqT, D_, D_);
  wcast_kernel<<<dim3(D_/32,  D_/32,  L_), tb, 0, stream>>>(Wk, wkT, D_, D_);
  wcast_kernel<<<dim3(D_/32,  D_/32,  L_), tb, 0, stream>>>(Wv, wvT, D_, D_);
  wcast_kernel<<<dim3(D_/32,  D_/32,  L_), tb, 0, stream>>>(Wo, woT, D_, D_);
  wcast_kernel<<<dim3(FF_/32, D_/32,  L_), tb, 0, stream>>>(W1, w1T, D_, FF_);
  wcast_kernel<<<dim3(D_/32,  FF_/32, L_), tb, 0, stream>>>(W2, w2T, FF_, D_);
  rel8_kernel<<<N_ * N_ / 1024, 256, 0, stream>>>(rel, rel8);

  hipMemcpyAsync(xw, x, (size_t)N_ * D_ * 4, hipMemcpyDeviceToDevice, stream);

  for (int l = 0; l < L_; ++l){
    ln_kernel<1><<<N_, 64, 0, stream>>>(xw, ln1g + l * D_, ln1b + l * D_, xnb, nullptr);
    gemm_kernel<1,0,0,0,1><<<dim3(768/64, N_/64), 256, 0, stream>>>(
        xnb, wqT + (size_t)l * D_ * D_, wkT + (size_t)l * D_ * D_, wvT + (size_t)l * D_ * D_,
        bq + l * D_, bk + l * D_, bv + l * D_,
        nullptr, nullptr, qkvb, vbt, N_, 768, D_, 0, 0, 0);
    qr_kernel<<<N_, 320, 0, stream>>>(qb, rke + (size_t)l * R_ * DK_, qr);
    // pass 1: S[h][i][j] = q.k (raw), f16, transposed store (A=K rows=j, B=Q rows=i)
    gemm_kernel<0,0,0,0,0,1><<<dim3(N_/64, N_/64, H_), 256, 0, stream>>>(
        kb, qb, nullptr, nullptr, nullptr, nullptr, nullptr,
        nullptr, nullptr, Sbuf, nullptr, N_, N_, DK_,
        (long)N_ * DK_, (long)N_ * DK_, (long)N_ * N_);
    // pass 2: exact row softmax + bias + bins
    sm_kernel<<<dim3(N_/4, H_), 256, 0, stream>>>(
        Sbuf, qr, (const unsigned char*)rel8, rve + (size_t)l * R_ * DK_, Pbuf, o2b);
    // pass 3: O = P@V^T + o2
    pv_kernel<<<dim3(N_/64, H_), 256, 0, stream>>>(Pbuf, vbt, o2b, obf);
    gemm_kernel<0,0,1,1,0><<<dim3(D_/64, N_/64), 256, 0, stream>>>(
        obf, woT + (size_t)l * D_ * D_, nullptr, nullptr,
        bo + l * D_, nullptr, nullptr,
        xw, xw, nullptr, nullptr, N_, D_, D_, 0, 0, 0);
    ln_kernel<1><<<N_, 64, 0, stream>>>(xw, ln2g + l * D_, ln2b + l * D_, xnb, nullptr);
    gemm_kernel<0,1,0,0,1><<<dim3(FF_/64, N_/64), 256, 0, stream>>>(
        xnb, w1T + (size_t)l * D_ * FF_, nullptr, nullptr,
        b1 + l * FF_, nullptr, nullptr,
        nullptr, nullptr, hidb, nullptr, N_, FF_, D_, 0, 0, 0);
    gemm_kernel<0,0,1,1,0><<<dim3(D_/64, N_/64), 256, 0, stream>>>(
        hidb, w2T + (size_t)l * FF_ * D_, nullptr, nullptr,
        b2 + l * D_, nullptr, nullptr,
        xw, xw, nullptr, nullptr, N_, D_, FF_, 0, 0, 0);
  }
  ln_kernel<0><<<N_, 64, 0, stream>>>(xw, lnfg, lnfb, nullptr, (float*)d_out);
}

// Round 10
// 888.626 us; speedup vs baseline: 1.0614x; 1.0614x over previous
//
#include <hip/hip_runtime.h>
#include <stdint.h>

#define L_ 8
#define D_ 256
#define H_ 8
#define DK_ 32
#define FF_ 1024
#define R_ 37
#define N_ 1024

// scale * log2(e): attention runs in exp2 domain
#define SCL (0.17677669529663689f * 1.4426950408889634f)

typedef float f4v __attribute__((ext_vector_type(4)));
typedef short b8v __attribute__((ext_vector_type(8)));

__device__ __forceinline__ ushort f2b(float f){
  union { float f; uint32_t u; } x; x.f = f;
  return (ushort)((x.u + 0x7FFFu + ((x.u >> 16) & 1u)) >> 16);
}
__device__ __forceinline__ float b2f(ushort u){
  union { uint32_t u; float f; } x; x.u = ((uint32_t)u) << 16;
  return x.f;
}
__device__ __forceinline__ ushort f2h(float f){
  union { _Float16 h; ushort u; } x; x.h = (_Float16)f;
  return x.u;
}
__device__ __forceinline__ float h2f(ushort u){
  union { ushort u; _Float16 h; } x; x.u = u;
  return (float)x.h;
}
__device__ __forceinline__ float ex2(float x){ return __builtin_amdgcn_exp2f(x); }

// native LDS float add (fire-and-forget; DS pipe is in-order per wave)
__device__ __forceinline__ void lds_fadd(float* p, float v){
  asm volatile("ds_add_f32 %0, %1" :: "v"((uint)(uintptr_t)p), "v"(v) : "memory");
}

// ---------------- weight transpose + cast: src [L][K][Nc] f32 -> dst [L][Nc][K] bf16
__global__ __launch_bounds__(256)
void wcast_kernel(const float* __restrict__ src, ushort* __restrict__ dst, int K, int Nc){
  __shared__ float t[32][33];
  int l = blockIdx.z;
  long base = (long)l * K * Nc;
  int n0 = blockIdx.x * 32, k0 = blockIdx.y * 32;
  int tx = threadIdx.x, ty = threadIdx.y; // (32,8)
  #pragma unroll
  for (int r = 0; r < 32; r += 8)
    t[ty + r][tx] = src[base + (long)(k0 + ty + r) * Nc + n0 + tx];
  __syncthreads();
  #pragma unroll
  for (int r = 0; r < 32; r += 8)
    dst[base + (long)(n0 + ty + r) * K + k0 + tx] = f2b(t[tx][ty + r]);
}

// ---------------- rel int32 -> uint8 (values < 37), once per call
__global__ __launch_bounds__(256)
void rel8_kernel(const int* __restrict__ rel, uint* __restrict__ rel8){
  long idx = (long)blockIdx.x * 256 + threadIdx.x;
  int4 v = ((const int4*)rel)[idx];
  rel8[idx] = (uint)(v.x & 255) | ((uint)(v.y & 255) << 8)
            | ((uint)(v.z & 255) << 16) | ((uint)(v.w & 255) << 24);
}

// ---------------- LayerNorm
template<int OUTB>
__global__ __launch_bounds__(64)
void ln_kernel(const float* __restrict__ x, const float* __restrict__ g, const float* __restrict__ b,
               ushort* __restrict__ ob, float* __restrict__ of){
  int row = blockIdx.x, lane = threadIdx.x;
  float4 v = ((const float4*)(x + (long)row * D_))[lane];
  float s = v.x + v.y + v.z + v.w;
  float s2 = v.x*v.x + v.y*v.y + v.z*v.z + v.w*v.w;
  #pragma unroll
  for (int o = 32; o; o >>= 1){ s += __shfl_xor(s, o); s2 += __shfl_xor(s2, o); }
  float mu = s * (1.f / D_);
  float var = (s2 - D_ * mu * mu) * (1.f / (D_ - 1));
  var = fmaxf(var, 0.f);
  float inv = 1.f / (sqrtf(var) + 1e-6f);
  float4 gv = ((const float4*)g)[lane];
  float4 bv = ((const float4*)b)[lane];
  float o0 = gv.x * (v.x - mu) * inv + bv.x;
  float o1 = gv.y * (v.y - mu) * inv + bv.y;
  float o2 = gv.z * (v.z - mu) * inv + bv.z;
  float o3 = gv.w * (v.w - mu) * inv + bv.w;
  if (OUTB){
    ushort4 u; u.x = f2b(o0); u.y = f2b(o1); u.z = f2b(o2); u.w = f2b(o3);
    ((ushort4*)ob)[(long)row * 64 + lane] = u;
  } else {
    float4 o; o.x = o0; o.y = o1; o.z = o2; o.w = o3;
    ((float4*)of)[(long)row * 64 + lane] = o;
  }
}

// ---------------- bf16 MFMA GEMM (QKV / scores / generic modes)
template<int QKV, int RELU, int RESID, int OUTF, int OUTB, int OUTH = 0>
__global__ __launch_bounds__(256)
void gemm_kernel(const ushort* __restrict__ A,
                 const ushort* __restrict__ W0, const ushort* __restrict__ W1p, const ushort* __restrict__ W2p,
                 const float* __restrict__ B0, const float* __restrict__ B1p, const float* __restrict__ B2p,
                 float* __restrict__ resid, float* __restrict__ outF, ushort* __restrict__ outB,
                 ushort* __restrict__ outB2,
                 int M, int Nc, int K, long aB, long wB, long oB){
  __shared__ ushort Al[64 * 48];
  __shared__ ushort Bl[64 * 48];
  int tid = threadIdx.x;
  int lane = tid & 63, w = tid >> 6;
  int wm = w >> 1, wn = w & 1;
  int bn0 = blockIdx.x * 64, bm0 = blockIdx.y * 64;
  long zb = blockIdx.z;
  A += zb * aB;
  const ushort* WT; const float* bias; int wn0;
  if (QKV){
    int which = bn0 >> 8;
    WT = which == 0 ? W0 : (which == 1 ? W1p : W2p);
    bias = which == 0 ? B0 : (which == 1 ? B1p : B2p);
    wn0 = bn0 & 255;
  } else { WT = W0; bias = B0; wn0 = bn0; }
  WT += zb * wB;

  int r4 = tid >> 2, c8 = (tid & 3) * 8;
  const ushort* ag = A + (long)(bm0 + r4) * K + c8;
  const ushort* bg = WT + (long)(wn0 + r4) * K + c8;

  f4v acc[2][2];
  #pragma unroll
  for (int i = 0; i < 2; ++i)
    #pragma unroll
    for (int j = 0; j < 2; ++j)
      acc[i][j] = (f4v){0.f, 0.f, 0.f, 0.f};

  int l16 = lane & 15, lg = lane >> 4;
  int arow0 = (wm * 32 + l16) * 48 + lg * 8;
  int brow0 = (wn * 32 + l16) * 48 + lg * 8;

  for (int k0 = 0; k0 < K; k0 += 32){
    b8v a8 = *(const b8v*)(ag + k0);
    b8v b8 = *(const b8v*)(bg + k0);
    __syncthreads();
    *(b8v*)&Al[r4 * 48 + c8] = a8;
    *(b8v*)&Bl[r4 * 48 + c8] = b8;
    __syncthreads();
    b8v a0 = *(const b8v*)&Al[arow0];
    b8v a1 = *(const b8v*)&Al[arow0 + 16 * 48];
    b8v b0 = *(const b8v*)&Bl[brow0];
    b8v b1 = *(const b8v*)&Bl[brow0 + 16 * 48];
    acc[0][0] = __builtin_amdgcn_mfma_f32_16x16x32_bf16(a0, b0, acc[0][0], 0, 0, 0);
    acc[0][1] = __builtin_amdgcn_mfma_f32_16x16x32_bf16(a0, b1, acc[0][1], 0, 0, 0);
    acc[1][0] = __builtin_amdgcn_mfma_f32_16x16x32_bf16(a1, b0, acc[1][0], 0, 0, 0);
    acc[1][1] = __builtin_amdgcn_mfma_f32_16x16x32_bf16(a1, b1, acc[1][1], 0, 0, 0);
  }
  #pragma unroll
  for (int fi = 0; fi < 2; ++fi)
    #pragma unroll
    for (int fj = 0; fj < 2; ++fj){
      int row0 = bm0 + wm * 32 + fi * 16 + lg * 4;
      int col = bn0 + wn * 32 + fj * 16 + l16;
      if (OUTH){
        ushort4 pk;
        pk.x = f2h(acc[fi][fj][0]); pk.y = f2h(acc[fi][fj][1]);
        pk.z = f2h(acc[fi][fj][2]); pk.w = f2h(acc[fi][fj][3]);
        *(ushort4*)(outB + zb * oB + (long)col * 1024 + row0) = pk;
        continue;
      }
      float vv[4];
      #pragma unroll
      for (int j = 0; j < 4; ++j) vv[j] = acc[fi][fj][j] + bias[QKV ? (col & 255) : col];
      if (QKV){
        int which = col >> 8, hh = (col >> 5) & 7, dk = col & 31;
        if (which == 2){
          ushort4 pk; pk.x = f2b(vv[0]); pk.y = f2b(vv[1]); pk.z = f2b(vv[2]); pk.w = f2b(vv[3]);
          *(ushort4*)(outB2 + (long)hh * 32768 + (long)dk * 1024 + row0) = pk;
        } else {
          #pragma unroll
          for (int j = 0; j < 4; ++j)
            outB[(long)which * 262144 + (long)hh * 32768 + (long)(row0 + j) * 32 + dk] = f2b(vv[j]);
        }
      } else {
        #pragma unroll
        for (int j = 0; j < 4; ++j){
          float v = vv[j];
          if (RELU) v = fmaxf(v, 0.f);
          long idx = (long)(row0 + j) * Nc + col;
          if (RESID) v += resid[idx];
          if (OUTF) outF[idx] = v;
          if (OUTB) outB[idx] = f2b(v);
        }
      }
    }
}

// ---------------- qr[h][i][r] (padded to 40) = SCL * q[h,i,:] . rel_k_emb[r]
__global__ __launch_bounds__(320)
void qr_kernel(const ushort* __restrict__ qb, const float* __restrict__ rke, float* __restrict__ qr){
  __shared__ float ql[256];
  int i = blockIdx.x, t = threadIdx.x;
  if (t < 256){
    int h = t >> 5, dk = t & 31;
    ql[t] = b2f(qb[(long)((h << 10) + i) * 32 + dk]);
  }
  __syncthreads();
  if (t < H_ * R_){
    int h = t / R_, r = t - h * R_;
    const float* qh = &ql[h * DK_];
    const float* e = rke + r * DK_;
    float acc = 0.f;
    #pragma unroll
    for (int d = 0; d < DK_; ++d) acc += qh[d] * e[d];
    qr[((long)(h << 10) + i) * 40 + r] = acc * SCL;
  }
}

// ---------------- softmax A/B: one wave per (head,row). exact full-row softmax.
// VAR 0 (smA): bins via 8-copy LDS atomics (collision degree / 8)
// VAR 1 (smB): bins via per-lane register binning + shfl fold (zero atomics)
template<int VAR>
__global__ __launch_bounds__(256)
void smab_kernel(const ushort* __restrict__ S, const float* __restrict__ qr,
                 const unsigned char* __restrict__ rel8, const float* __restrict__ rve,
                 ushort* __restrict__ P, float* __restrict__ o2){
  __shared__ float qrl[4][40];
  __shared__ float rvl[R_ * 32];
  __shared__ float bins[4][8 * 41];
  int tid = threadIdx.x, lane = tid & 63, w = tid >> 6;
  int h = blockIdx.y, i = blockIdx.x * 4 + w;
  long rowq = (long)(h << 10) + i;

  for (int idx = tid; idx < R_ * 32; idx += 256) rvl[idx] = rve[idx];
  for (int idx = tid; idx < 4 * 8 * 41; idx += 256) ((float*)bins)[idx] = 0.f;
  if (lane < 40) qrl[w][lane] = qr[rowq * 40 + lane];
  __syncthreads();

  const ushort* Srow = S + rowq * 1024 + lane * 16;
  b8v s0 = *(const b8v*)Srow;
  b8v s1 = *(const b8v*)(Srow + 8);
  uint4 rr = *(const uint4*)(rel8 + (long)i * 1024 + lane * 16);
  uint rw[4] = { rr.x, rr.y, rr.z, rr.w };

  int rix[16];
  #pragma unroll
  for (int q = 0; q < 4; ++q)
    #pragma unroll
    for (int e = 0; e < 4; ++e)
      rix[q * 4 + e] = (rw[q] >> (8 * e)) & 255;

  float sv[16];
  #pragma unroll
  for (int e = 0; e < 8; ++e){
    sv[e]     = h2f((ushort)s0[e]) * SCL + qrl[w][rix[e]];
    sv[8 + e] = h2f((ushort)s1[e]) * SCL + qrl[w][rix[8 + e]];
  }
  float m = sv[0];
  #pragma unroll
  for (int e = 1; e < 16; ++e) m = fmaxf(m, sv[e]);
  #pragma unroll
  for (int o = 1; o < 64; o <<= 1) m = fmaxf(m, __shfl_xor(m, o));

  float p[16], ls = 0.f;
  #pragma unroll
  for (int e = 0; e < 16; ++e){ p[e] = ex2(sv[e] - m); ls += p[e]; }
  #pragma unroll
  for (int o = 1; o < 64; o <<= 1) ls += __shfl_xor(ls, o);
  float rinv = 1.f / ls;

  if (VAR == 0){
    // 8 replicated copies: lanes sharing (lane>>3) collide, 8-way max
    float* bc = &bins[w][(lane >> 3) * 41];
    #pragma unroll
    for (int e = 0; e < 16; ++e) lds_fadd(&bc[rix[e]], p[e]);
  } else {
    // register binning: static-indexed bp[37], unrolled selects (pure VALU)
    float bp[R_];
    #pragma unroll
    for (int r = 0; r < R_; ++r){
      float a = 0.f;
      #pragma unroll
      for (int e = 0; e < 16; ++e) a += (rix[e] == r) ? p[e] : 0.f;
      bp[r] = a;
    }
    // fold 8 lanes per group via shfl, then one conflict-free write per group
    #pragma unroll
    for (int st = 1; st < 8; st <<= 1)
      #pragma unroll
      for (int r = 0; r < R_; ++r) bp[r] += __shfl_xor(bp[r], st);
    if ((lane & 7) == 0){
      float* bc = &bins[w][(lane >> 3) * 41];
      #pragma unroll
      for (int r = 0; r < R_; ++r) bc[r] = bp[r];
    }
  }

  // normalized P bf16
  b8v po0, po1;
  #pragma unroll
  for (int e = 0; e < 8; ++e){
    po0[e] = (short)f2b(p[e] * rinv);
    po1[e] = (short)f2b(p[8 + e] * rinv);
  }
  *(b8v*)(P + rowq * 1024 + lane * 16) = po0;
  *(b8v*)(P + rowq * 1024 + lane * 16 + 8) = po1;

  // fold 8 copies (same-wave DS ops are in-order; no barrier needed)
  if (lane < R_){
    float b = 0.f;
    #pragma unroll
    for (int c = 0; c < 8; ++c) b += bins[w][c * 41 + lane];
    bins[w][lane] = b;
  }

  // o2[rowq][d] = (bins @ rve)[d] / l
  int d = lane & 31, half = lane >> 5;
  float acc = 0.f;
  if (half == 0){
    #pragma unroll
    for (int r = 0; r < 19; ++r) acc += bins[w][r] * rvl[r * 32 + d];
  } else {
    #pragma unroll
    for (int r = 19; r < R_; ++r) acc += bins[w][r] * rvl[r * 32 + d];
  }
  acc += __shfl_xor(acc, 32);
  if (lane < 32) o2[rowq * 32 + d] = acc * rinv;
}

// ---------------- PV pass: O[h][i][d] = P[h][i][:] @ V^T[h][d][:] + o2
__global__ __launch_bounds__(256)
void pv_kernel(const ushort* __restrict__ P, const ushort* __restrict__ vbt,
               const float* __restrict__ o2, ushort* __restrict__ ob){
  __shared__ ushort Al[64 * 48];
  __shared__ ushort Bl[32 * 48];
  int tid = threadIdx.x, lane = tid & 63, w = tid >> 6;
  int l16 = lane & 15, g = lane >> 4;
  int i0 = blockIdx.x * 64, h = blockIdx.y;
  const ushort* Ph = P + (long)h * 1024 * 1024;
  const ushort* Vh = vbt + (long)h * 32 * 1024;
  int r4 = tid >> 2, c8 = (tid & 3) * 8;

  f4v acc0 = (f4v){0,0,0,0}, acc1 = (f4v){0,0,0,0};
  int arow = (w * 16 + l16) * 48 + g * 8;
  int brow0 = l16 * 48 + g * 8, brow1 = (16 + l16) * 48 + g * 8;

  for (int k0 = 0; k0 < 1024; k0 += 32){
    b8v a8 = *(const b8v*)(Ph + (long)(i0 + r4) * 1024 + k0 + c8);
    b8v b8;
    if (tid < 128) b8 = *(const b8v*)(Vh + (long)r4 * 1024 + k0 + c8);
    __syncthreads();
    *(b8v*)&Al[r4 * 48 + c8] = a8;
    if (tid < 128) *(b8v*)&Bl[r4 * 48 + c8] = b8;
    __syncthreads();
    b8v a0 = *(const b8v*)&Al[arow];
    b8v b0 = *(const b8v*)&Bl[brow0];
    b8v b1 = *(const b8v*)&Bl[brow1];
    acc0 = __builtin_amdgcn_mfma_f32_16x16x32_bf16(a0, b0, acc0, 0, 0, 0);
    acc1 = __builtin_amdgcn_mfma_f32_16x16x32_bf16(a0, b1, acc1, 0, 0, 0);
  }
  #pragma unroll
  for (int e = 0; e < 4; ++e){
    int i = i0 + w * 16 + g * 4 + e;
    long ob2 = ((long)(h << 10) + i) * 32;
    float v0 = acc0[e] + o2[ob2 + l16];
    float v1 = acc1[e] + o2[ob2 + 16 + l16];
    ob[(long)i * 256 + h * 32 + l16] = f2b(v0);
    ob[(long)i * 256 + h * 32 + 16 + l16] = f2b(v1);
  }
}

extern "C" void kernel_launch(void* const* d_in, const int* in_sizes, int n_in,
                              void* d_out, int out_size, void* d_ws, size_t ws_size,
                              hipStream_t stream){
  const float* x    = (const float*)d_in[0];
  const int*   rel  = (const int*)d_in[1];
  const float* Wq   = (const float*)d_in[2];
  const float* bq   = (const float*)d_in[3];
  const float* Wk   = (const float*)d_in[4];
  const float* bk   = (const float*)d_in[5];
  const float* Wv   = (const float*)d_in[6];
  const float* bv   = (const float*)d_in[7];
  const float* Wo   = (const float*)d_in[8];
  const float* bo   = (const float*)d_in[9];
  const float* rke  = (const float*)d_in[10];
  const float* rve  = (const float*)d_in[11];
  const float* W1   = (const float*)d_in[12];
  const float* b1   = (const float*)d_in[13];
  const float* W2   = (const float*)d_in[14];
  const float* b2   = (const float*)d_in[15];
  const float* ln1g = (const float*)d_in[16];
  const float* ln1b = (const float*)d_in[17];
  const float* ln2g = (const float*)d_in[18];
  const float* ln2b = (const float*)d_in[19];
  const float* lnfg = (const float*)d_in[20];
  const float* lnfb = (const float*)d_in[21];

  char* wsb = (char*)d_ws;
  size_t off = 0;
  auto alloc = [&](size_t bytes){ void* p = wsb + off; off += (bytes + 255) & ~255ull; return p; };
  float*  xw   = (float*) alloc((size_t)N_ * D_ * 4);
  ushort* qkvb = (ushort*)alloc((size_t)3 * H_ * N_ * DK_ * 2);
  ushort* vbt  = (ushort*)alloc((size_t)H_ * DK_ * N_ * 2);
  float*  qr   = (float*) alloc((size_t)H_ * N_ * 40 * 4);
  ushort* xnb  = (ushort*)alloc((size_t)N_ * D_ * 2);
  ushort* obf  = (ushort*)alloc((size_t)N_ * D_ * 2);
  ushort* hidb = (ushort*)alloc((size_t)N_ * FF_ * 2);
  uint*   rel8 = (uint*)  alloc((size_t)N_ * N_);
  ushort* Sbuf = (ushort*)alloc((size_t)H_ * N_ * N_ * 2);
  ushort* Pbuf = (ushort*)alloc((size_t)H_ * N_ * N_ * 2);
  float*  o2b  = (float*) alloc((size_t)H_ * N_ * DK_ * 4);
  ushort* wqT  = (ushort*)alloc((size_t)L_ * D_ * D_ * 2);
  ushort* wkT  = (ushort*)alloc((size_t)L_ * D_ * D_ * 2);
  ushort* wvT  = (ushort*)alloc((size_t)L_ * D_ * D_ * 2);
  ushort* woT  = (ushort*)alloc((size_t)L_ * D_ * D_ * 2);
  ushort* w1T  = (ushort*)alloc((size_t)L_ * D_ * FF_ * 2);
  ushort* w2T  = (ushort*)alloc((size_t)L_ * D_ * FF_ * 2);
  (void)ws_size; (void)in_sizes; (void)n_in; (void)out_size;

  ushort* qb = qkvb;
  ushort* kb = qkvb + (size_t)H_ * N_ * DK_;

  dim3 tb(32, 8);
  wcast_kernel<<<dim3(D_/32,  D_/32,  L_), tb, 0, stream>>>(Wq, wqT, D_, D_);
  wcast_kernel<<<dim3(D_/32,  D_/32,  L_), tb, 0, stream>>>(Wk, wkT, D_, D_);
  wcast_kernel<<<dim3(D_/32,  D_/32,  L_), tb, 0, stream>>>(Wv, wvT, D_, D_);
  wcast_kernel<<<dim3(D_/32,  D_/32,  L_), tb, 0, stream>>>(Wo, woT, D_, D_);
  wcast_kernel<<<dim3(FF_/32, D_/32,  L_), tb, 0, stream>>>(W1, w1T, D_, FF_);
  wcast_kernel<<<dim3(D_/32,  FF_/32, L_), tb, 0, stream>>>(W2, w2T, FF_, D_);
  rel8_kernel<<<N_ * N_ / 1024, 256, 0, stream>>>(rel, rel8);

  hipMemcpyAsync(xw, x, (size_t)N_ * D_ * 4, hipMemcpyDeviceToDevice, stream);

  for (int l = 0; l < L_; ++l){
    ln_kernel<1><<<N_, 64, 0, stream>>>(xw, ln1g + l * D_, ln1b + l * D_, xnb, nullptr);
    gemm_kernel<1,0,0,0,1><<<dim3(768/64, N_/64), 256, 0, stream>>>(
        xnb, wqT + (size_t)l * D_ * D_, wkT + (size_t)l * D_ * D_, wvT + (size_t)l * D_ * D_,
        bq + l * D_, bk + l * D_, bv + l * D_,
        nullptr, nullptr, qkvb, vbt, N_, 768, D_, 0, 0, 0);
    qr_kernel<<<N_, 320, 0, stream>>>(qb, rke + (size_t)l * R_ * DK_, qr);
    gemm_kernel<0,0,0,0,0,1><<<dim3(N_/64, N_/64, H_), 256, 0, stream>>>(
        kb, qb, nullptr, nullptr, nullptr, nullptr, nullptr,
        nullptr, nullptr, Sbuf, nullptr, N_, N_, DK_,
        (long)N_ * DK_, (long)N_ * DK_, (long)N_ * N_);
    if (l & 1)
      smab_kernel<1><<<dim3(N_/4, H_), 256, 0, stream>>>(
          Sbuf, qr, (const unsigned char*)rel8, rve + (size_t)l * R_ * DK_, Pbuf, o2b);
    else
      smab_kernel<0><<<dim3(N_/4, H_), 256, 0, stream>>>(
          Sbuf, qr, (const unsigned char*)rel8, rve + (size_t)l * R_ * DK_, Pbuf, o2b);
    pv_kernel<<<dim3(N_/64, H_), 256, 0, stream>>>(Pbuf, vbt, o2b, obf);
    gemm_kernel<0,0,1,1,0><<<dim3(D_/64, N_/64), 256, 0, stream>>>(
        obf, woT + (size_t)l * D_ * D_, nullptr, nullptr,
        bo + l * D_, nullptr, nullptr,
        xw, xw, nullptr, nullptr, N_, D_, D_, 0, 0, 0);
    ln_kernel<1><<<N_, 64, 0, stream>>>(xw, ln2g + l * D_, ln2b + l * D_, xnb, nullptr);
    gemm_kernel<0,1,0,0,1><<<dim3(FF_/64, N_/64), 256, 0, stream>>>(
        xnb, w1T + (size_t)l * D_ * FF_, nullptr, nullptr,
        b1 + l * FF_, nullptr, nullptr,
        nullptr, nullptr, hidb, nullptr, N_, FF_, D_, 0, 0, 0);
    gemm_kernel<0,0,1,1,0><<<dim3(D_/64, N_/64), 256, 0, stream>>>(
        hidb, w2T + (size_t)l * FF_ * D_, nullptr, nullptr,
        b2 + l * D_, nullptr, nullptr,
        xw, xw, nullptr, nullptr, N_, D_, FF_, 0, 0, 0);
  }
  ln_kernel<0><<<N_, 64, 0, stream>>>(xw, lnfg, lnfb, nullptr, (float*)d_out);
}

// Round 11
// 887.635 us; speedup vs baseline: 1.0626x; 1.0011x over previous
//
#include <hip/hip_runtime.h>
#include <stdint.h>

#define L_ 8
#define D_ 256
#define H_ 8
#define DK_ 32
#define FF_ 1024
#define R_ 37
#define N_ 1024

// scale * log2(e): attention runs in exp2 domain
#define SCL (0.17677669529663689f * 1.4426950408889634f)

typedef float f4v __attribute__((ext_vector_type(4)));
typedef short b8v __attribute__((ext_vector_type(8)));

__device__ __forceinline__ ushort f2b(float f){
  union { float f; uint32_t u; } x; x.f = f;
  return (ushort)((x.u + 0x7FFFu + ((x.u >> 16) & 1u)) >> 16);
}
__device__ __forceinline__ float b2f(ushort u){
  union { uint32_t u; float f; } x; x.u = ((uint32_t)u) << 16;
  return x.f;
}
__device__ __forceinline__ ushort f2h(float f){
  union { _Float16 h; ushort u; } x; x.h = (_Float16)f;
  return x.u;
}
__device__ __forceinline__ float h2f(ushort u){
  union { ushort u; _Float16 h; } x; x.u = u;
  return (float)x.h;
}
__device__ __forceinline__ float ex2(float x){ return __builtin_amdgcn_exp2f(x); }

// native LDS float add (fire-and-forget; DS pipe is in-order per wave)
__device__ __forceinline__ void lds_fadd(float* p, float v){
  asm volatile("ds_add_f32 %0, %1" :: "v"((uint)(uintptr_t)p), "v"(v) : "memory");
}

// ---------------- weight transpose + cast: src [L][K][Nc] f32 -> dst [L][Nc][K] bf16
__global__ __launch_bounds__(256)
void wcast_kernel(const float* __restrict__ src, ushort* __restrict__ dst, int K, int Nc){
  __shared__ float t[32][33];
  int l = blockIdx.z;
  long base = (long)l * K * Nc;
  int n0 = blockIdx.x * 32, k0 = blockIdx.y * 32;
  int tx = threadIdx.x, ty = threadIdx.y; // (32,8)
  #pragma unroll
  for (int r = 0; r < 32; r += 8)
    t[ty + r][tx] = src[base + (long)(k0 + ty + r) * Nc + n0 + tx];
  __syncthreads();
  #pragma unroll
  for (int r = 0; r < 32; r += 8)
    dst[base + (long)(n0 + ty + r) * K + k0 + tx] = f2b(t[tx][ty + r]);
}

// ---------------- rel int32 -> uint8 (values < 37), once per call
__global__ __launch_bounds__(256)
void rel8_kernel(const int* __restrict__ rel, uint* __restrict__ rel8){
  long idx = (long)blockIdx.x * 256 + threadIdx.x;
  int4 v = ((const int4*)rel)[idx];
  rel8[idx] = (uint)(v.x & 255) | ((uint)(v.y & 255) << 8)
            | ((uint)(v.z & 255) << 16) | ((uint)(v.w & 255) << 24);
}

// ---------------- LayerNorm
template<int OUTB>
__global__ __launch_bounds__(64)
void ln_kernel(const float* __restrict__ x, const float* __restrict__ g, const float* __restrict__ b,
               ushort* __restrict__ ob, float* __restrict__ of){
  int row = blockIdx.x, lane = threadIdx.x;
  float4 v = ((const float4*)(x + (long)row * D_))[lane];
  float s = v.x + v.y + v.z + v.w;
  float s2 = v.x*v.x + v.y*v.y + v.z*v.z + v.w*v.w;
  #pragma unroll
  for (int o = 32; o; o >>= 1){ s += __shfl_xor(s, o); s2 += __shfl_xor(s2, o); }
  float mu = s * (1.f / D_);
  float var = (s2 - D_ * mu * mu) * (1.f / (D_ - 1));
  var = fmaxf(var, 0.f);
  float inv = 1.f / (sqrtf(var) + 1e-6f);
  float4 gv = ((const float4*)g)[lane];
  float4 bv = ((const float4*)b)[lane];
  float o0 = gv.x * (v.x - mu) * inv + bv.x;
  float o1 = gv.y * (v.y - mu) * inv + bv.y;
  float o2 = gv.z * (v.z - mu) * inv + bv.z;
  float o3 = gv.w * (v.w - mu) * inv + bv.w;
  if (OUTB){
    ushort4 u; u.x = f2b(o0); u.y = f2b(o1); u.z = f2b(o2); u.w = f2b(o3);
    ((ushort4*)ob)[(long)row * 64 + lane] = u;
  } else {
    float4 o; o.x = o0; o.y = o1; o.z = o2; o.w = o3;
    ((float4*)of)[(long)row * 64 + lane] = o;
  }
}

// ---------------- bf16 MFMA GEMM (QKV / scores / generic modes)
template<int QKV, int RELU, int RESID, int OUTF, int OUTB, int OUTH = 0>
__global__ __launch_bounds__(256)
void gemm_kernel(const ushort* __restrict__ A,
                 const ushort* __restrict__ W0, const ushort* __restrict__ W1p, const ushort* __restrict__ W2p,
                 const float* __restrict__ B0, const float* __restrict__ B1p, const float* __restrict__ B2p,
                 float* __restrict__ resid, float* __restrict__ outF, ushort* __restrict__ outB,
                 ushort* __restrict__ outB2,
                 int M, int Nc, int K, long aB, long wB, long oB){
  __shared__ ushort Al[64 * 48];
  __shared__ ushort Bl[64 * 48];
  int tid = threadIdx.x;
  int lane = tid & 63, w = tid >> 6;
  int wm = w >> 1, wn = w & 1;
  int bn0 = blockIdx.x * 64, bm0 = blockIdx.y * 64;
  long zb = blockIdx.z;
  A += zb * aB;
  const ushort* WT; const float* bias; int wn0;
  if (QKV){
    int which = bn0 >> 8;
    WT = which == 0 ? W0 : (which == 1 ? W1p : W2p);
    bias = which == 0 ? B0 : (which == 1 ? B1p : B2p);
    wn0 = bn0 & 255;
  } else { WT = W0; bias = B0; wn0 = bn0; }
  WT += zb * wB;

  int r4 = tid >> 2, c8 = (tid & 3) * 8;
  const ushort* ag = A + (long)(bm0 + r4) * K + c8;
  const ushort* bg = WT + (long)(wn0 + r4) * K + c8;

  f4v acc[2][2];
  #pragma unroll
  for (int i = 0; i < 2; ++i)
    #pragma unroll
    for (int j = 0; j < 2; ++j)
      acc[i][j] = (f4v){0.f, 0.f, 0.f, 0.f};

  int l16 = lane & 15, lg = lane >> 4;
  int arow0 = (wm * 32 + l16) * 48 + lg * 8;
  int brow0 = (wn * 32 + l16) * 48 + lg * 8;

  for (int k0 = 0; k0 < K; k0 += 32){
    b8v a8 = *(const b8v*)(ag + k0);
    b8v b8 = *(const b8v*)(bg + k0);
    __syncthreads();
    *(b8v*)&Al[r4 * 48 + c8] = a8;
    *(b8v*)&Bl[r4 * 48 + c8] = b8;
    __syncthreads();
    b8v a0 = *(const b8v*)&Al[arow0];
    b8v a1 = *(const b8v*)&Al[arow0 + 16 * 48];
    b8v b0 = *(const b8v*)&Bl[brow0];
    b8v b1 = *(const b8v*)&Bl[brow0 + 16 * 48];
    acc[0][0] = __builtin_amdgcn_mfma_f32_16x16x32_bf16(a0, b0, acc[0][0], 0, 0, 0);
    acc[0][1] = __builtin_amdgcn_mfma_f32_16x16x32_bf16(a0, b1, acc[0][1], 0, 0, 0);
    acc[1][0] = __builtin_amdgcn_mfma_f32_16x16x32_bf16(a1, b0, acc[1][0], 0, 0, 0);
    acc[1][1] = __builtin_amdgcn_mfma_f32_16x16x32_bf16(a1, b1, acc[1][1], 0, 0, 0);
  }
  #pragma unroll
  for (int fi = 0; fi < 2; ++fi)
    #pragma unroll
    for (int fj = 0; fj < 2; ++fj){
      int row0 = bm0 + wm * 32 + fi * 16 + lg * 4;
      int col = bn0 + wn * 32 + fj * 16 + l16;
      if (OUTH){
        ushort4 pk;
        pk.x = f2h(acc[fi][fj][0]); pk.y = f2h(acc[fi][fj][1]);
        pk.z = f2h(acc[fi][fj][2]); pk.w = f2h(acc[fi][fj][3]);
        *(ushort4*)(outB + zb * oB + (long)col * 1024 + row0) = pk;
        continue;
      }
      float vv[4];
      #pragma unroll
      for (int j = 0; j < 4; ++j) vv[j] = acc[fi][fj][j] + bias[QKV ? (col & 255) : col];
      if (QKV){
        int which = col >> 8, hh = (col >> 5) & 7, dk = col & 31;
        if (which == 2){
          ushort4 pk; pk.x = f2b(vv[0]); pk.y = f2b(vv[1]); pk.z = f2b(vv[2]); pk.w = f2b(vv[3]);
          *(ushort4*)(outB2 + (long)hh * 32768 + (long)dk * 1024 + row0) = pk;
        } else {
          #pragma unroll
          for (int j = 0; j < 4; ++j)
            outB[(long)which * 262144 + (long)hh * 32768 + (long)(row0 + j) * 32 + dk] = f2b(vv[j]);
        }
      } else {
        #pragma unroll
        for (int j = 0; j < 4; ++j){
          float v = vv[j];
          if (RELU) v = fmaxf(v, 0.f);
          long idx = (long)(row0 + j) * Nc + col;
          if (RESID) v += resid[idx];
          if (OUTF) outF[idx] = v;
          if (OUTB) outB[idx] = f2b(v);
        }
      }
    }
}

// ---------------- qr[h][i][r] (padded to 40) = SCL * q[h,i,:] . rel_k_emb[r]
__global__ __launch_bounds__(320)
void qr_kernel(const ushort* __restrict__ qb, const float* __restrict__ rke, float* __restrict__ qr){
  __shared__ float ql[256];
  int i = blockIdx.x, t = threadIdx.x;
  if (t < 256){
    int h = t >> 5, dk = t & 31;
    ql[t] = b2f(qb[(long)((h << 10) + i) * 32 + dk]);
  }
  __syncthreads();
  if (t < H_ * R_){
    int h = t / R_, r = t - h * R_;
    const float* qh = &ql[h * DK_];
    const float* e = rke + r * DK_;
    float acc = 0.f;
    #pragma unroll
    for (int d = 0; d < DK_; ++d) acc += qh[d] * e[d];
    qr[((long)(h << 10) + i) * 40 + r] = acc * SCL;
  }
}

// ---------------- merged softmax + PV: block = (32 rows, head), 512 threads
// phase 1: deep-batched S/rel loads -> exact row softmax -> normalized P in LDS + bins
// phase 2: PV MFMA from LDS-P with staged V^T, + bins@rve, write output
#define PST 1048  // P_l row stride in ushorts (x2B = 2096, 16B aligned)
__global__ __launch_bounds__(512)
void spv_kernel(const ushort* __restrict__ S, const float* __restrict__ qr,
                const unsigned char* __restrict__ rel8, const float* __restrict__ rve,
                const ushort* __restrict__ vbt, ushort* __restrict__ ob){
  __shared__ ushort P_l[32 * PST];       // 67KB  normalized P (bf16), resident
  __shared__ ushort Bl[4][32 * 48];      // 12.3KB V^T chunk per k-quarter
  __shared__ float part[2][4][16 * 33];  // 16.9KB PV partials per (rowgroup, kq)
  __shared__ float qr_l[32 * 40];        // 5.1KB
  __shared__ float rvl[R_ * 32];         // 4.7KB
  __shared__ float binsw[8][8 * 41];     // 10.5KB per-wave 8-copy bin workspace
  __shared__ float binsout[32 * 41];     // 5.4KB normalized bins per row

  int tid = threadIdx.x, lane = tid & 63, w = tid >> 6;
  int l16 = lane & 15, g = lane >> 4;
  int i0 = blockIdx.x * 32, h = blockIdx.y;

  for (int idx = tid; idx < 32 * 40; idx += 512)
    qr_l[idx] = qr[((long)(h << 10) + i0) * 40 + idx];
  for (int idx = tid; idx < R_ * 32; idx += 512) rvl[idx] = rve[idx];
  for (int idx = tid; idx < 8 * 8 * 41; idx += 512) ((float*)binsw)[idx] = 0.f;
  __syncthreads();

  // ---- phase 1: softmax. wave w owns rows w*4 .. w*4+3. all loads issued first.
  b8v s0[4], s1[4];
  uint4 rr4[4];
  #pragma unroll
  for (int r = 0; r < 4; ++r){
    long rowq = (long)(h << 10) + i0 + w * 4 + r;
    const ushort* Sr = S + rowq * 1024 + lane * 16;
    s0[r] = *(const b8v*)Sr;
    s1[r] = *(const b8v*)(Sr + 8);
    rr4[r] = *(const uint4*)(rel8 + (long)(i0 + w * 4 + r) * 1024 + lane * 16);
  }
  #pragma unroll
  for (int r = 0; r < 4; ++r){
    int row = w * 4 + r;
    uint rw[4] = { rr4[r].x, rr4[r].y, rr4[r].z, rr4[r].w };
    int rix[16];
    #pragma unroll
    for (int q = 0; q < 4; ++q)
      #pragma unroll
      for (int e = 0; e < 4; ++e)
        rix[q * 4 + e] = (rw[q] >> (8 * e)) & 255;
    float sv[16];
    #pragma unroll
    for (int e = 0; e < 8; ++e){
      sv[e]     = h2f((ushort)s0[r][e]) * SCL + qr_l[row * 40 + rix[e]];
      sv[8 + e] = h2f((ushort)s1[r][e]) * SCL + qr_l[row * 40 + rix[8 + e]];
    }
    float m = sv[0];
    #pragma unroll
    for (int e = 1; e < 16; ++e) m = fmaxf(m, sv[e]);
    #pragma unroll
    for (int o = 1; o < 64; o <<= 1) m = fmaxf(m, __shfl_xor(m, o));
    float p[16], ls = 0.f;
    #pragma unroll
    for (int e = 0; e < 16; ++e){ p[e] = ex2(sv[e] - m); ls += p[e]; }
    #pragma unroll
    for (int o = 1; o < 64; o <<= 1) ls += __shfl_xor(ls, o);
    float rinv = 1.f / ls;

    float* bc = &binsw[w][(lane >> 3) * 41];
    #pragma unroll
    for (int e = 0; e < 16; ++e) lds_fadd(&bc[rix[e]], p[e]);

    b8v po0, po1;
    #pragma unroll
    for (int e = 0; e < 8; ++e){
      po0[e] = (short)f2b(p[e] * rinv);
      po1[e] = (short)f2b(p[8 + e] * rinv);
    }
    *(b8v*)&P_l[row * PST + lane * 16] = po0;
    *(b8v*)&P_l[row * PST + lane * 16 + 8] = po1;

    // fold 8 copies (same-wave DS ops are in-order), store normalized bins, reset
    if (lane < R_){
      float b = 0.f;
      #pragma unroll
      for (int c = 0; c < 8; ++c) b += binsw[w][c * 41 + lane];
      binsout[row * 41 + lane] = b * rinv;
    }
    #pragma unroll
    for (int c = 0; c < 8; ++c)
      if (lane < 41) binsw[w][c * 41 + lane] = 0.f;
  }
  __syncthreads();

  // ---- phase 2: PV. wave = (rowgroup rg, k-quarter kq). 8 iterations of 32-k chunks.
  int rg = w & 1, kq = w >> 1;
  f4v acc0 = (f4v){0,0,0,0}, acc1 = (f4v){0,0,0,0};
  int arowbase = (rg * 16 + l16) * PST + g * 8;
  int brow0 = l16 * 48 + g * 8, brow1 = (16 + l16) * 48 + g * 8;
  int sq = tid >> 7, st = tid & 127;
  int sr4 = st >> 2, sc8 = (st & 3) * 8;
  const ushort* vsrc = vbt + (long)h * 32768 + (long)sr4 * 1024 + sq * 256 + sc8;

  for (int t = 0; t < 8; ++t){
    *(b8v*)&Bl[sq][sr4 * 48 + sc8] = *(const b8v*)(vsrc + t * 32);
    __syncthreads();
    int k0 = kq * 256 + t * 32;
    b8v a0 = *(const b8v*)&P_l[arowbase + k0];
    b8v b0 = *(const b8v*)&Bl[kq][brow0];
    b8v b1 = *(const b8v*)&Bl[kq][brow1];
    acc0 = __builtin_amdgcn_mfma_f32_16x16x32_bf16(a0, b0, acc0, 0, 0, 0);
    acc1 = __builtin_amdgcn_mfma_f32_16x16x32_bf16(a0, b1, acc1, 0, 0, 0);
    __syncthreads();
  }
  #pragma unroll
  for (int e = 0; e < 4; ++e){
    part[rg][kq][(g * 4 + e) * 33 + l16] = acc0[e];
    part[rg][kq][(g * 4 + e) * 33 + 16 + l16] = acc1[e];
  }
  __syncthreads();

  // ---- final fold: o = sum_kq part + bins @ rve, write bf16
  for (int slot = tid; slot < 1024; slot += 512){
    int row = slot >> 5, d = slot & 31;
    int rg2 = row >> 4, rl = row & 15;
    float o = 0.f;
    #pragma unroll
    for (int q = 0; q < 4; ++q) o += part[rg2][q][rl * 33 + d];
    float o2 = 0.f;
    #pragma unroll
    for (int r = 0; r < R_; ++r) o2 += binsout[row * 41 + r] * rvl[r * 32 + d];
    ob[(long)(i0 + row) * 256 + h * 32 + d] = f2b(o + o2);
  }
}

extern "C" void kernel_launch(void* const* d_in, const int* in_sizes, int n_in,
                              void* d_out, int out_size, void* d_ws, size_t ws_size,
                              hipStream_t stream){
  const float* x    = (const float*)d_in[0];
  const int*   rel  = (const int*)d_in[1];
  const float* Wq   = (const float*)d_in[2];
  const float* bq   = (const float*)d_in[3];
  const float* Wk   = (const float*)d_in[4];
  const float* bk   = (const float*)d_in[5];
  const float* Wv   = (const float*)d_in[6];
  const float* bv   = (const float*)d_in[7];
  const float* Wo   = (const float*)d_in[8];
  const float* bo   = (const float*)d_in[9];
  const float* rke  = (const float*)d_in[10];
  const float* rve  = (const float*)d_in[11];
  const float* W1   = (const float*)d_in[12];
  const float* b1   = (const float*)d_in[13];
  const float* W2   = (const float*)d_in[14];
  const float* b2   = (const float*)d_in[15];
  const float* ln1g = (const float*)d_in[16];
  const float* ln1b = (const float*)d_in[17];
  const float* ln2g = (const float*)d_in[18];
  const float* ln2b = (const float*)d_in[19];
  const float* lnfg = (const float*)d_in[20];
  const float* lnfb = (const float*)d_in[21];

  char* wsb = (char*)d_ws;
  size_t off = 0;
  auto alloc = [&](size_t bytes){ void* p = wsb + off; off += (bytes + 255) & ~255ull; return p; };
  float*  xw   = (float*) alloc((size_t)N_ * D_ * 4);
  ushort* qkvb = (ushort*)alloc((size_t)3 * H_ * N_ * DK_ * 2);
  ushort* vbt  = (ushort*)alloc((size_t)H_ * DK_ * N_ * 2);
  float*  qr   = (float*) alloc((size_t)H_ * N_ * 40 * 4);
  ushort* xnb  = (ushort*)alloc((size_t)N_ * D_ * 2);
  ushort* obf  = (ushort*)alloc((size_t)N_ * D_ * 2);
  ushort* hidb = (ushort*)alloc((size_t)N_ * FF_ * 2);
  uint*   rel8 = (uint*)  alloc((size_t)N_ * N_);
  ushort* Sbuf = (ushort*)alloc((size_t)H_ * N_ * N_ * 2);
  ushort* wqT  = (ushort*)alloc((size_t)L_ * D_ * D_ * 2);
  ushort* wkT  = (ushort*)alloc((size_t)L_ * D_ * D_ * 2);
  ushort* wvT  = (ushort*)alloc((size_t)L_ * D_ * D_ * 2);
  ushort* woT  = (ushort*)alloc((size_t)L_ * D_ * D_ * 2);
  ushort* w1T  = (ushort*)alloc((size_t)L_ * D_ * FF_ * 2);
  ushort* w2T  = (ushort*)alloc((size_t)L_ * D_ * FF_ * 2);
  (void)ws_size; (void)in_sizes; (void)n_in; (void)out_size;

  ushort* qb = qkvb;
  ushort* kb = qkvb + (size_t)H_ * N_ * DK_;

  dim3 tb(32, 8);
  wcast_kernel<<<dim3(D_/32,  D_/32,  L_), tb, 0, stream>>>(Wq, wqT, D_, D_);
  wcast_kernel<<<dim3(D_/32,  D_/32,  L_), tb, 0, stream>>>(Wk, wkT, D_, D_);
  wcast_kernel<<<dim3(D_/32,  D_/32,  L_), tb, 0, stream>>>(Wv, wvT, D_, D_);
  wcast_kernel<<<dim3(D_/32,  D_/32,  L_), tb, 0, stream>>>(Wo, woT, D_, D_);
  wcast_kernel<<<dim3(FF_/32, D_/32,  L_), tb, 0, stream>>>(W1, w1T, D_, FF_);
  wcast_kernel<<<dim3(D_/32,  FF_/32, L_), tb, 0, stream>>>(W2, w2T, FF_, D_);
  rel8_kernel<<<N_ * N_ / 1024, 256, 0, stream>>>(rel, rel8);

  hipMemcpyAsync(xw, x, (size_t)N_ * D_ * 4, hipMemcpyDeviceToDevice, stream);

  for (int l = 0; l < L_; ++l){
    ln_kernel<1><<<N_, 64, 0, stream>>>(xw, ln1g + l * D_, ln1b + l * D_, xnb, nullptr);
    gemm_kernel<1,0,0,0,1><<<dim3(768/64, N_/64), 256, 0, stream>>>(
        xnb, wqT + (size_t)l * D_ * D_, wkT + (size_t)l * D_ * D_, wvT + (size_t)l * D_ * D_,
        bq + l * D_, bk + l * D_, bv + l * D_,
        nullptr, nullptr, qkvb, vbt, N_, 768, D_, 0, 0, 0);
    qr_kernel<<<N_, 320, 0, stream>>>(qb, rke + (size_t)l * R_ * DK_, qr);
    gemm_kernel<0,0,0,0,0,1><<<dim3(N_/64, N_/64, H_), 256, 0, stream>>>(
        kb, qb, nullptr, nullptr, nullptr, nullptr, nullptr,
        nullptr, nullptr, Sbuf, nullptr, N_, N_, DK_,
        (long)N_ * DK_, (long)N_ * DK_, (long)N_ * N_);
    spv_kernel<<<dim3(N_/32, H_), 512, 0, stream>>>(
        Sbuf, qr, (const unsigned char*)rel8, rve + (size_t)l * R_ * DK_, vbt, obf);
    gemm_kernel<0,0,1,1,0><<<dim3(D_/64, N_/64), 256, 0, stream>>>(
        obf, woT + (size_t)l * D_ * D_, nullptr, nullptr,
        bo + l * D_, nullptr, nullptr,
        xw, xw, nullptr, nullptr, N_, D_, D_, 0, 0, 0);
    ln_kernel<1><<<N_, 64, 0, stream>>>(xw, ln2g + l * D_, ln2b + l * D_, xnb, nullptr);
    gemm_kernel<0,1,0,0,1><<<dim3(FF_/64, N_/64), 256, 0, stream>>>(
        xnb, w1T + (size_t)l * D_ * FF_, nullptr, nullptr,
        b1 + l * FF_, nullptr, nullptr,
        nullptr, nullptr, hidb, nullptr, N_, FF_, D_, 0, 0, 0);
    gemm_kernel<0,0,1,1,0><<<dim3(D_/64, N_/64), 256, 0, stream>>>(
        hidb, w2T + (size_t)l * FF_ * D_, nullptr, nullptr,
        b2 + l * D_, nullptr, nullptr,
        xw, xw, nullptr, nullptr, N_, D_, FF_, 0, 0, 0);
  }
  ln_kernel<0><<<N_, 64, 0, stream>>>(xw, lnfg, lnfb, nullptr, (float*)d_out);
}

// Round 12
// 875.699 us; speedup vs baseline: 1.0771x; 1.0136x over previous
//
#include <hip/hip_runtime.h>
#include <stdint.h>

#define L_ 8
#define D_ 256
#define H_ 8
#define DK_ 32
#define FF_ 1024
#define R_ 37
#define N_ 1024

// scale * log2(e): attention runs in exp2 domain
#define SCL (0.17677669529663689f * 1.4426950408889634f)

typedef float f4v __attribute__((ext_vector_type(4)));
typedef short b8v __attribute__((ext_vector_type(8)));

__device__ __forceinline__ ushort f2b(float f){
  union { float f; uint32_t u; } x; x.f = f;
  return (ushort)((x.u + 0x7FFFu + ((x.u >> 16) & 1u)) >> 16);
}
__device__ __forceinline__ float b2f(ushort u){
  union { uint32_t u; float f; } x; x.u = ((uint32_t)u) << 16;
  return x.f;
}
__device__ __forceinline__ ushort f2h(float f){
  union { _Float16 h; ushort u; } x; x.h = (_Float16)f;
  return x.u;
}
__device__ __forceinline__ float h2f(ushort u){
  union { ushort u; _Float16 h; } x; x.u = u;
  return (float)x.h;
}
__device__ __forceinline__ float ex2(float x){ return __builtin_amdgcn_exp2f(x); }

// native LDS float add (fire-and-forget; DS pipe is in-order per wave)
__device__ __forceinline__ void lds_fadd(float* p, float v){
  asm volatile("ds_add_f32 %0, %1" :: "v"((uint)(uintptr_t)p), "v"(v) : "memory");
}

// ---------------- weight transpose + cast: src [L][K][Nc] f32 -> dst [L][Nc][K] bf16
__global__ __launch_bounds__(256)
void wcast_kernel(const float* __restrict__ src, ushort* __restrict__ dst, int K, int Nc){
  __shared__ float t[32][33];
  int l = blockIdx.z;
  long base = (long)l * K * Nc;
  int n0 = blockIdx.x * 32, k0 = blockIdx.y * 32;
  int tx = threadIdx.x, ty = threadIdx.y; // (32,8)
  #pragma unroll
  for (int r = 0; r < 32; r += 8)
    t[ty + r][tx] = src[base + (long)(k0 + ty + r) * Nc + n0 + tx];
  __syncthreads();
  #pragma unroll
  for (int r = 0; r < 32; r += 8)
    dst[base + (long)(n0 + ty + r) * K + k0 + tx] = f2b(t[tx][ty + r]);
}

// ---------------- rel int32 -> uint8 (values < 37), once per call
__global__ __launch_bounds__(256)
void rel8_kernel(const int* __restrict__ rel, uint* __restrict__ rel8){
  long idx = (long)blockIdx.x * 256 + threadIdx.x;
  int4 v = ((const int4*)rel)[idx];
  rel8[idx] = (uint)(v.x & 255) | ((uint)(v.y & 255) << 8)
            | ((uint)(v.z & 255) << 16) | ((uint)(v.w & 255) << 24);
}

// ---------------- LayerNorm
template<int OUTB>
__global__ __launch_bounds__(64)
void ln_kernel(const float* __restrict__ x, const float* __restrict__ g, const float* __restrict__ b,
               ushort* __restrict__ ob, float* __restrict__ of){
  int row = blockIdx.x, lane = threadIdx.x;
  float4 v = ((const float4*)(x + (long)row * D_))[lane];
  float s = v.x + v.y + v.z + v.w;
  float s2 = v.x*v.x + v.y*v.y + v.z*v.z + v.w*v.w;
  #pragma unroll
  for (int o = 32; o; o >>= 1){ s += __shfl_xor(s, o); s2 += __shfl_xor(s2, o); }
  float mu = s * (1.f / D_);
  float var = (s2 - D_ * mu * mu) * (1.f / (D_ - 1));
  var = fmaxf(var, 0.f);
  float inv = 1.f / (sqrtf(var) + 1e-6f);
  float4 gv = ((const float4*)g)[lane];
  float4 bv = ((const float4*)b)[lane];
  float o0 = gv.x * (v.x - mu) * inv + bv.x;
  float o1 = gv.y * (v.y - mu) * inv + bv.y;
  float o2 = gv.z * (v.z - mu) * inv + bv.z;
  float o3 = gv.w * (v.w - mu) * inv + bv.w;
  if (OUTB){
    ushort4 u; u.x = f2b(o0); u.y = f2b(o1); u.z = f2b(o2); u.w = f2b(o3);
    ((ushort4*)ob)[(long)row * 64 + lane] = u;
  } else {
    float4 o; o.x = o0; o.y = o1; o.z = o2; o.w = o3;
    ((float4*)of)[(long)row * 64 + lane] = o;
  }
}

// ---------------- bf16 MFMA GEMM (QKV / scores / generic modes)
template<int QKV, int RELU, int RESID, int OUTF, int OUTB, int OUTH = 0>
__global__ __launch_bounds__(256)
void gemm_kernel(const ushort* __restrict__ A,
                 const ushort* __restrict__ W0, const ushort* __restrict__ W1p, const ushort* __restrict__ W2p,
                 const float* __restrict__ B0, const float* __restrict__ B1p, const float* __restrict__ B2p,
                 float* __restrict__ resid, float* __restrict__ outF, ushort* __restrict__ outB,
                 ushort* __restrict__ outB2,
                 int M, int Nc, int K, long aB, long wB, long oB){
  __shared__ ushort Al[64 * 48];
  __shared__ ushort Bl[64 * 48];
  int tid = threadIdx.x;
  int lane = tid & 63, w = tid >> 6;
  int wm = w >> 1, wn = w & 1;
  int bn0 = blockIdx.x * 64, bm0 = blockIdx.y * 64;
  long zb = blockIdx.z;
  A += zb * aB;
  const ushort* WT; const float* bias; int wn0;
  if (QKV){
    int which = bn0 >> 8;
    WT = which == 0 ? W0 : (which == 1 ? W1p : W2p);
    bias = which == 0 ? B0 : (which == 1 ? B1p : B2p);
    wn0 = bn0 & 255;
  } else { WT = W0; bias = B0; wn0 = bn0; }
  WT += zb * wB;

  int r4 = tid >> 2, c8 = (tid & 3) * 8;
  const ushort* ag = A + (long)(bm0 + r4) * K + c8;
  const ushort* bg = WT + (long)(wn0 + r4) * K + c8;

  f4v acc[2][2];
  #pragma unroll
  for (int i = 0; i < 2; ++i)
    #pragma unroll
    for (int j = 0; j < 2; ++j)
      acc[i][j] = (f4v){0.f, 0.f, 0.f, 0.f};

  int l16 = lane & 15, lg = lane >> 4;
  int arow0 = (wm * 32 + l16) * 48 + lg * 8;
  int brow0 = (wn * 32 + l16) * 48 + lg * 8;

  for (int k0 = 0; k0 < K; k0 += 32){
    b8v a8 = *(const b8v*)(ag + k0);
    b8v b8 = *(const b8v*)(bg + k0);
    __syncthreads();
    *(b8v*)&Al[r4 * 48 + c8] = a8;
    *(b8v*)&Bl[r4 * 48 + c8] = b8;
    __syncthreads();
    b8v a0 = *(const b8v*)&Al[arow0];
    b8v a1 = *(const b8v*)&Al[arow0 + 16 * 48];
    b8v b0 = *(const b8v*)&Bl[brow0];
    b8v b1 = *(const b8v*)&Bl[brow0 + 16 * 48];
    acc[0][0] = __builtin_amdgcn_mfma_f32_16x16x32_bf16(a0, b0, acc[0][0], 0, 0, 0);
    acc[0][1] = __builtin_amdgcn_mfma_f32_16x16x32_bf16(a0, b1, acc[0][1], 0, 0, 0);
    acc[1][0] = __builtin_amdgcn_mfma_f32_16x16x32_bf16(a1, b0, acc[1][0], 0, 0, 0);
    acc[1][1] = __builtin_amdgcn_mfma_f32_16x16x32_bf16(a1, b1, acc[1][1], 0, 0, 0);
  }
  #pragma unroll
  for (int fi = 0; fi < 2; ++fi)
    #pragma unroll
    for (int fj = 0; fj < 2; ++fj){
      int row0 = bm0 + wm * 32 + fi * 16 + lg * 4;
      int col = bn0 + wn * 32 + fj * 16 + l16;
      if (OUTH){
        ushort4 pk;
        pk.x = f2h(acc[fi][fj][0]); pk.y = f2h(acc[fi][fj][1]);
        pk.z = f2h(acc[fi][fj][2]); pk.w = f2h(acc[fi][fj][3]);
        *(ushort4*)(outB + zb * oB + (long)col * 1024 + row0) = pk;
        continue;
      }
      float vv[4];
      #pragma unroll
      for (int j = 0; j < 4; ++j) vv[j] = acc[fi][fj][j] + bias[QKV ? (col & 255) : col];
      if (QKV){
        int which = col >> 8, hh = (col >> 5) & 7, dk = col & 31;
        if (which == 2){
          ushort4 pk; pk.x = f2b(vv[0]); pk.y = f2b(vv[1]); pk.z = f2b(vv[2]); pk.w = f2b(vv[3]);
          *(ushort4*)(outB2 + (long)hh * 32768 + (long)dk * 1024 + row0) = pk;
        } else {
          #pragma unroll
          for (int j = 0; j < 4; ++j)
            outB[(long)which * 262144 + (long)hh * 32768 + (long)(row0 + j) * 32 + dk] = f2b(vv[j]);
        }
      } else {
        #pragma unroll
        for (int j = 0; j < 4; ++j){
          float v = vv[j];
          if (RELU) v = fmaxf(v, 0.f);
          long idx = (long)(row0 + j) * Nc + col;
          if (RESID) v += resid[idx];
          if (OUTF) outF[idx] = v;
          if (OUTB) outB[idx] = f2b(v);
        }
      }
    }
}

// ---------------- qr[h][i][r] (padded to 40) = SCL * q[h,i,:] . rel_k_emb[r]
__global__ __launch_bounds__(320)
void qr_kernel(const ushort* __restrict__ qb, const float* __restrict__ rke, float* __restrict__ qr){
  __shared__ float ql[256];
  int i = blockIdx.x, t = threadIdx.x;
  if (t < 256){
    int h = t >> 5, dk = t & 31;
    ql[t] = b2f(qb[(long)((h << 10) + i) * 32 + dk]);
  }
  __syncthreads();
  if (t < H_ * R_){
    int h = t / R_, r = t - h * R_;
    const float* qh = &ql[h * DK_];
    const float* e = rke + r * DK_;
    float acc = 0.f;
    #pragma unroll
    for (int d = 0; d < DK_; ++d) acc += qh[d] * e[d];
    qr[((long)(h << 10) + i) * 40 + r] = acc * SCL;
  }
}

// ---------------- merged softmax + PV with XCD-local S reads.
// sc writes S i-chunk [64c, 64c+64) entirely from XCD c%8 (linear id%8 = bx%8).
// spv remaps its linear block id B so XCD(B)=B%8 == (i-chunk)%8 -> S reads are L2-local.
#define PST 1048  // P_l row stride in ushorts (x2B = 2096, 16B aligned)
__global__ __launch_bounds__(512)
void spv_kernel(const ushort* __restrict__ S, const float* __restrict__ qr,
                const unsigned char* __restrict__ rel8, const float* __restrict__ rve,
                const ushort* __restrict__ vbt, ushort* __restrict__ ob){
  __shared__ ushort P_l[32 * PST];       // 67KB  normalized P (bf16), resident
  __shared__ ushort Bl[4][32 * 48];      // 12.3KB V^T chunk per k-quarter
  __shared__ float part[2][4][16 * 33];  // 16.9KB PV partials per (rowgroup, kq)
  __shared__ float qr_l[32 * 40];        // 5.1KB
  __shared__ float rvl[R_ * 32];         // 4.7KB
  __shared__ float binsw[8][8 * 41];     // 10.5KB per-wave 8-copy bin workspace
  __shared__ float binsout[32 * 41];     // 5.4KB normalized bins per row

  int tid = threadIdx.x, lane = tid & 63, w = tid >> 6;
  int l16 = lane & 15, g = lane >> 4;

  // XCD-consistent block remap: B%8 == (i-chunk-of-64)%8
  int B = blockIdx.x;
  int s8 = B & 7, u = B >> 3;
  int h = u & 7, v = u >> 3;
  int xb = 2 * (s8 + 8 * (v & 1)) + (v >> 1);
  int i0 = xb * 32;

  for (int idx = tid; idx < 32 * 40; idx += 512)
    qr_l[idx] = qr[((long)(h << 10) + i0) * 40 + idx];
  for (int idx = tid; idx < R_ * 32; idx += 512) rvl[idx] = rve[idx];
  for (int idx = tid; idx < 8 * 8 * 41; idx += 512) ((float*)binsw)[idx] = 0.f;
  __syncthreads();

  // ---- phase 1: softmax. wave w owns rows w*4 .. w*4+3. all loads issued first.
  b8v s0[4], s1[4];
  uint4 rr4[4];
  #pragma unroll
  for (int r = 0; r < 4; ++r){
    long rowq = (long)(h << 10) + i0 + w * 4 + r;
    const ushort* Sr = S + rowq * 1024 + lane * 16;
    s0[r] = *(const b8v*)Sr;
    s1[r] = *(const b8v*)(Sr + 8);
    rr4[r] = *(const uint4*)(rel8 + (long)(i0 + w * 4 + r) * 1024 + lane * 16);
  }
  #pragma unroll
  for (int r = 0; r < 4; ++r){
    int row = w * 4 + r;
    uint rw[4] = { rr4[r].x, rr4[r].y, rr4[r].z, rr4[r].w };
    int rix[16];
    #pragma unroll
    for (int q = 0; q < 4; ++q)
      #pragma unroll
      for (int e = 0; e < 4; ++e)
        rix[q * 4 + e] = (rw[q] >> (8 * e)) & 255;
    float sv[16];
    #pragma unroll
    for (int e = 0; e < 8; ++e){
      sv[e]     = h2f((ushort)s0[r][e]) * SCL + qr_l[row * 40 + rix[e]];
      sv[8 + e] = h2f((ushort)s1[r][e]) * SCL + qr_l[row * 40 + rix[8 + e]];
    }
    float m = sv[0];
    #pragma unroll
    for (int e = 1; e < 16; ++e) m = fmaxf(m, sv[e]);
    #pragma unroll
    for (int o = 1; o < 64; o <<= 1) m = fmaxf(m, __shfl_xor(m, o));
    float p[16], ls = 0.f;
    #pragma unroll
    for (int e = 0; e < 16; ++e){ p[e] = ex2(sv[e] - m); ls += p[e]; }
    #pragma unroll
    for (int o = 1; o < 64; o <<= 1) ls += __shfl_xor(ls, o);
    float rinv = 1.f / ls;

    float* bc = &binsw[w][(lane >> 3) * 41];
    #pragma unroll
    for (int e = 0; e < 16; ++e) lds_fadd(&bc[rix[e]], p[e]);

    b8v po0, po1;
    #pragma unroll
    for (int e = 0; e < 8; ++e){
      po0[e] = (short)f2b(p[e] * rinv);
      po1[e] = (short)f2b(p[8 + e] * rinv);
    }
    *(b8v*)&P_l[row * PST + lane * 16] = po0;
    *(b8v*)&P_l[row * PST + lane * 16 + 8] = po1;

    // fold 8 copies (same-wave DS ops are in-order), store normalized bins, reset
    if (lane < R_){
      float b = 0.f;
      #pragma unroll
      for (int c = 0; c < 8; ++c) b += binsw[w][c * 41 + lane];
      binsout[row * 41 + lane] = b * rinv;
    }
    #pragma unroll
    for (int c = 0; c < 8; ++c)
      if (lane < 41) binsw[w][c * 41 + lane] = 0.f;
  }
  __syncthreads();

  // ---- phase 2: PV. wave = (rowgroup rg, k-quarter kq). 8 iterations of 32-k chunks.
  int rg = w & 1, kq = w >> 1;
  f4v acc0 = (f4v){0,0,0,0}, acc1 = (f4v){0,0,0,0};
  int arowbase = (rg * 16 + l16) * PST + g * 8;
  int brow0 = l16 * 48 + g * 8, brow1 = (16 + l16) * 48 + g * 8;
  int sq = tid >> 7, st = tid & 127;
  int sr4 = st >> 2, sc8 = (st & 3) * 8;
  const ushort* vsrc = vbt + (long)h * 32768 + (long)sr4 * 1024 + sq * 256 + sc8;

  for (int t = 0; t < 8; ++t){
    *(b8v*)&Bl[sq][sr4 * 48 + sc8] = *(const b8v*)(vsrc + t * 32);
    __syncthreads();
    int k0 = kq * 256 + t * 32;
    b8v a0 = *(const b8v*)&P_l[arowbase + k0];
    b8v b0 = *(const b8v*)&Bl[kq][brow0];
    b8v b1 = *(const b8v*)&Bl[kq][brow1];
    acc0 = __builtin_amdgcn_mfma_f32_16x16x32_bf16(a0, b0, acc0, 0, 0, 0);
    acc1 = __builtin_amdgcn_mfma_f32_16x16x32_bf16(a0, b1, acc1, 0, 0, 0);
    __syncthreads();
  }
  #pragma unroll
  for (int e = 0; e < 4; ++e){
    part[rg][kq][(g * 4 + e) * 33 + l16] = acc0[e];
    part[rg][kq][(g * 4 + e) * 33 + 16 + l16] = acc1[e];
  }
  __syncthreads();

  // ---- final fold: o = sum_kq part + bins @ rve, write bf16
  for (int slot = tid; slot < 1024; slot += 512){
    int row = slot >> 5, d = slot & 31;
    int rg2 = row >> 4, rl = row & 15;
    float o = 0.f;
    #pragma unroll
    for (int q = 0; q < 4; ++q) o += part[rg2][q][rl * 33 + d];
    float o2 = 0.f;
    #pragma unroll
    for (int r = 0; r < R_; ++r) o2 += binsout[row * 41 + r] * rvl[r * 32 + d];
    ob[(long)(i0 + row) * 256 + h * 32 + d] = f2b(o + o2);
  }
}

extern "C" void kernel_launch(void* const* d_in, const int* in_sizes, int n_in,
                              void* d_out, int out_size, void* d_ws, size_t ws_size,
                              hipStream_t stream){
  const float* x    = (const float*)d_in[0];
  const int*   rel  = (const int*)d_in[1];
  const float* Wq   = (const float*)d_in[2];
  const float* bq   = (const float*)d_in[3];
  const float* Wk   = (const float*)d_in[4];
  const float* bk   = (const float*)d_in[5];
  const float* Wv   = (const float*)d_in[6];
  const float* bv   = (const float*)d_in[7];
  const float* Wo   = (const float*)d_in[8];
  const float* bo   = (const float*)d_in[9];
  const float* rke  = (const float*)d_in[10];
  const float* rve  = (const float*)d_in[11];
  const float* W1   = (const float*)d_in[12];
  const float* b1   = (const float*)d_in[13];
  const float* W2   = (const float*)d_in[14];
  const float* b2   = (const float*)d_in[15];
  const float* ln1g = (const float*)d_in[16];
  const float* ln1b = (const float*)d_in[17];
  const float* ln2g = (const float*)d_in[18];
  const float* ln2b = (const float*)d_in[19];
  const float* lnfg = (const float*)d_in[20];
  const float* lnfb = (const float*)d_in[21];

  char* wsb = (char*)d_ws;
  size_t off = 0;
  auto alloc = [&](size_t bytes){ void* p = wsb + off; off += (bytes + 255) & ~255ull; return p; };
  float*  xw   = (float*) alloc((size_t)N_ * D_ * 4);
  ushort* qkvb = (ushort*)alloc((size_t)3 * H_ * N_ * DK_ * 2);
  ushort* vbt  = (ushort*)alloc((size_t)H_ * DK_ * N_ * 2);
  float*  qr   = (float*) alloc((size_t)H_ * N_ * 40 * 4);
  ushort* xnb  = (ushort*)alloc((size_t)N_ * D_ * 2);
  ushort* obf  = (ushort*)alloc((size_t)N_ * D_ * 2);
  ushort* hidb = (ushort*)alloc((size_t)N_ * FF_ * 2);
  uint*   rel8 = (uint*)  alloc((size_t)N_ * N_);
  ushort* Sbuf = (ushort*)alloc((size_t)H_ * N_ * N_ * 2);
  ushort* wqT  = (ushort*)alloc((size_t)L_ * D_ * D_ * 2);
  ushort* wkT  = (ushort*)alloc((size_t)L_ * D_ * D_ * 2);
  ushort* wvT  = (ushort*)alloc((size_t)L_ * D_ * D_ * 2);
  ushort* woT  = (ushort*)alloc((size_t)L_ * D_ * D_ * 2);
  ushort* w1T  = (ushort*)alloc((size_t)L_ * D_ * FF_ * 2);
  ushort* w2T  = (ushort*)alloc((size_t)L_ * D_ * FF_ * 2);
  (void)ws_size; (void)in_sizes; (void)n_in; (void)out_size;

  ushort* qb = qkvb;
  ushort* kb = qkvb + (size_t)H_ * N_ * DK_;

  dim3 tb(32, 8);
  wcast_kernel<<<dim3(D_/32,  D_/32,  L_), tb, 0, stream>>>(Wq, wqT, D_, D_);
  wcast_kernel<<<dim3(D_/32,  D_/32,  L_), tb, 0, stream>>>(Wk, wkT, D_, D_);
  wcast_kernel<<<dim3(D_/32,  D_/32,  L_), tb, 0, stream>>>(Wv, wvT, D_, D_);
  wcast_kernel<<<dim3(D_/32,  D_/32,  L_), tb, 0, stream>>>(Wo, woT, D_, D_);
  wcast_kernel<<<dim3(FF_/32, D_/32,  L_), tb, 0, stream>>>(W1, w1T, D_, FF_);
  wcast_kernel<<<dim3(D_/32,  FF_/32, L_), tb, 0, stream>>>(W2, w2T, FF_, D_);
  rel8_kernel<<<N_ * N_ / 1024, 256, 0, stream>>>(rel, rel8);

  hipMemcpyAsync(xw, x, (size_t)N_ * D_ * 4, hipMemcpyDeviceToDevice, stream);

  for (int l = 0; l < L_; ++l){
    ln_kernel<1><<<N_, 64, 0, stream>>>(xw, ln1g + l * D_, ln1b + l * D_, xnb, nullptr);
    gemm_kernel<1,0,0,0,1><<<dim3(768/64, N_/64), 256, 0, stream>>>(
        xnb, wqT + (size_t)l * D_ * D_, wkT + (size_t)l * D_ * D_, wvT + (size_t)l * D_ * D_,
        bq + l * D_, bk + l * D_, bv + l * D_,
        nullptr, nullptr, qkvb, vbt, N_, 768, D_, 0, 0, 0);
    qr_kernel<<<N_, 320, 0, stream>>>(qb, rke + (size_t)l * R_ * DK_, qr);
    gemm_kernel<0,0,0,0,0,1><<<dim3(N_/64, N_/64, H_), 256, 0, stream>>>(
        kb, qb, nullptr, nullptr, nullptr, nullptr, nullptr,
        nullptr, nullptr, Sbuf, nullptr, N_, N_, DK_,
        (long)N_ * DK_, (long)N_ * DK_, (long)N_ * N_);
    spv_kernel<<<dim3(256), 512, 0, stream>>>(
        Sbuf, qr, (const unsigned char*)rel8, rve + (size_t)l * R_ * DK_, vbt, obf);
    gemm_kernel<0,0,1,1,0><<<dim3(D_/64, N_/64), 256, 0, stream>>>(
        obf, woT + (size_t)l * D_ * D_, nullptr, nullptr,
        bo + l * D_, nullptr, nullptr,
        xw, xw, nullptr, nullptr, N_, D_, D_, 0, 0, 0);
    ln_kernel<1><<<N_, 64, 0, stream>>>(xw, ln2g + l * D_, ln2b + l * D_, xnb, nullptr);
    gemm_kernel<0,1,0,0,1><<<dim3(FF_/64, N_/64), 256, 0, stream>>>(
        xnb, w1T + (size_t)l * D_ * FF_, nullptr, nullptr,
        b1 + l * FF_, nullptr, nullptr,
        nullptr, nullptr, hidb, nullptr, N_, FF_, D_, 0, 0, 0);
    gemm_kernel<0,0,1,1,0><<<dim3(D_/64, N_/64), 256, 0, stream>>>(
        hidb, w2T + (size_t)l * FF_ * D_, nullptr, nullptr,
        b2 + l * D_, nullptr, nullptr,
        xw, xw, nullptr, nullptr, N_, D_, FF_, 0, 0, 0);
  }
  ln_kernel<0><<<N_, 64, 0, stream>>>(xw, lnfg, lnfb, nullptr, (float*)d_out);
}